// Round 3
// baseline (1201.602 us; speedup 1.0000x reference)
//
#include <hip/hip_runtime.h>
#include <hip/hip_bf16.h>

#define EPSV 1e-5f
#define NSHARD 8

// bf16x2 unpack (bf16 = top 16 bits of fp32)
__device__ inline float blo(unsigned u) { return __uint_as_float(u << 16); }
__device__ inline float bhi(unsigned u) { return __uint_as_float(u & 0xFFFF0000u); }

// ================= CSR build (sharded) =================

// cnt8[shard*N + dst] += 1 ; shard = blockIdx & 7 (must match k_fill!)
__global__ __launch_bounds__(256) void k_count(const int* __restrict__ dst,
                                               int* __restrict__ cnt8, int E, int N) {
    int i = blockIdx.x * 256 + threadIdx.x;
    int s = blockIdx.x & (NSHARD - 1);
    if (i < E) atomicAdd(&cnt8[s * N + dst[i]], 1);
}

// deg[d] = sum over shards
__global__ __launch_bounds__(256) void k_deg8(const int* __restrict__ cnt8,
                                              int* __restrict__ deg, int N) {
    int d = blockIdx.x * 256 + threadIdx.x;
    if (d >= N) return;
    int s = 0;
#pragma unroll
    for (int k = 0; k < NSHARD; k++) s += cnt8[k * N + d];
    deg[d] = s;
}

// scan phase 1: per-1024-chunk exclusive scan + chunk totals
__global__ __launch_bounds__(256) void k_scan1(const int* __restrict__ deg,
                                               int* __restrict__ rowptr,
                                               int* __restrict__ bsum, int N) {
    int t = threadIdx.x;
    int idx = blockIdx.x * 1024 + t * 4;
    int v[4], s = 0;
#pragma unroll
    for (int k = 0; k < 4; k++) { v[k] = (idx + k < N) ? deg[idx + k] : 0; s += v[k]; }
    __shared__ int ls[256];
    ls[t] = s;
    __syncthreads();
    for (int off = 1; off < 256; off <<= 1) {
        int x = (t >= off) ? ls[t - off] : 0;
        __syncthreads();
        ls[t] += x;
        __syncthreads();
    }
    if (t == 255) bsum[blockIdx.x] = ls[255];
    int run = (t == 0) ? 0 : ls[t - 1];
#pragma unroll
    for (int k = 0; k < 4; k++) {
        if (idx + k < N) rowptr[idx + k] = run;
        run += v[k];
    }
}

// scan phase 2: exclusive scan of chunk totals (B <= 256)
__global__ __launch_bounds__(256) void k_scan2(int* __restrict__ bsum, int B) {
    int t = threadIdx.x;
    __shared__ int ls[256];
    ls[t] = (t < B) ? bsum[t] : 0;
    __syncthreads();
    for (int off = 1; off < 256; off <<= 1) {
        int x = (t >= off) ? ls[t - off] : 0;
        __syncthreads();
        ls[t] += x;
        __syncthreads();
    }
    if (t < B) bsum[t] = (t == 0) ? 0 : ls[t - 1];
}

// scan phase 3: add chunk offsets
__global__ __launch_bounds__(256) void k_scan3(int* __restrict__ rowptr,
                                               const int* __restrict__ bsum, int N) {
    int i = blockIdx.x * 256 + threadIdx.x;
    if (i < N) rowptr[i] += bsum[i >> 10];
}

// per-(shard,dst) cursor init + rowend + dinv
__global__ __launch_bounds__(256) void k_curs(const int* __restrict__ cnt8,
                                              const int* __restrict__ rowptr,
                                              int* __restrict__ cur8,
                                              int* __restrict__ rowend,
                                              float* __restrict__ dinv, int N) {
    int d = blockIdx.x * 256 + threadIdx.x;
    if (d >= N) return;
    int base = rowptr[d];
    int run = base;
#pragma unroll
    for (int s = 0; s < NSHARD; s++) {
        cur8[s * N + d] = run;
        run += cnt8[s * N + d];
    }
    rowend[d] = run;
    dinv[d] = rsqrtf((float)(run - base) + 1.0f);
}

// scatter edges into CSR buckets via sharded cursors
__global__ __launch_bounds__(256) void k_fill(const int* __restrict__ src,
                                              const int* __restrict__ dst,
                                              int* __restrict__ cur8,
                                              int* __restrict__ colidx, int E, int N) {
    int i = blockIdx.x * 256 + threadIdx.x;
    int s = blockIdx.x & (NSHARD - 1);
    if (i < E) {
        int pos = atomicAdd(&cur8[s * N + dst[i]], 1);
        colidx[pos] = src[i];
    }
}

// ================= network =================

// h0 = relu(x @ W_in + b_in); wave per node, lane = out feature
__global__ __launch_bounds__(256) void k_input(const float* __restrict__ x,
                                               const float* __restrict__ Win,
                                               const float* __restrict__ bin,
                                               float* __restrict__ h, int N) {
    int t = blockIdx.x * 256 + threadIdx.x;
    int node = t >> 6, j = t & 63;
    if (node >= N) return;
    const float* xr = x + node * 12;
    float acc = bin[j];
#pragma unroll
    for (int k = 0; k < 12; k++) acc = fmaf(xr[k], Win[k * 64 + j], acc);
    h[t] = fmaxf(acc, 0.0f);
}

// hl (bf16) <- (h @ W) * dinv[node]
__global__ __launch_bounds__(256) void k_gemm(const float* __restrict__ W,
                                              const float* __restrict__ dinv,
                                              const float* __restrict__ h,
                                              __hip_bfloat16* __restrict__ hl, int N) {
    int j = threadIdx.x & 63;
    float w[64];
#pragma unroll
    for (int k = 0; k < 64; k++) w[k] = W[k * 64 + j];
    int wave = (blockIdx.x * 256 + threadIdx.x) >> 6;
    int nw = (gridDim.x * 256) >> 6;
    for (int node = wave; node < N; node += nw) {
        const float4* row = (const float4*)(h + node * 64);
        float acc = 0.0f;
#pragma unroll
        for (int kk = 0; kk < 16; kk++) {
            float4 r = row[kk];
            acc = fmaf(r.x, w[4 * kk + 0], acc);
            acc = fmaf(r.y, w[4 * kk + 1], acc);
            acc = fmaf(r.z, w[4 * kk + 2], acc);
            acc = fmaf(r.w, w[4 * kk + 3], acc);
        }
        hl[node * 64 + j] = __float2bfloat16(acc * dinv[node]);
    }
}

// gather: out[d] = dinv[d]*(hl[d] + sum_{s in in(d)} hl[s]) + b
// half-wave (32 lanes) per dst row; lane holds bf16x2 feature pair.
__global__ __launch_bounds__(256) void k_agg(const int* __restrict__ rowptr,
                                             const int* __restrict__ rowend,
                                             const int* __restrict__ colidx,
                                             const float* __restrict__ dinv,
                                             const unsigned* __restrict__ hl2,
                                             const float* __restrict__ b,
                                             float* __restrict__ out, int N) {
    int t = threadIdx.x;
    int hw = t >> 5, f = t & 31;
    int d = blockIdx.x * 8 + hw;
    if (d >= N) return;
    int e0 = rowptr[d], e1 = rowend[d];
    unsigned us = hl2[d * 32 + f];
    float a0 = blo(us), a1 = bhi(us);
    float b0 = 0.f, b1 = 0.f, c0 = 0.f, c1 = 0.f, g0 = 0.f, g1 = 0.f;
    int e = e0;
    for (; e + 4 <= e1; e += 4) {
        int s0 = colidx[e], s1 = colidx[e + 1], s2 = colidx[e + 2], s3 = colidx[e + 3];
        unsigned u0 = hl2[s0 * 32 + f], u1 = hl2[s1 * 32 + f];
        unsigned u2 = hl2[s2 * 32 + f], u3 = hl2[s3 * 32 + f];
        a0 += blo(u0); a1 += bhi(u0);
        b0 += blo(u1); b1 += bhi(u1);
        c0 += blo(u2); c1 += bhi(u2);
        g0 += blo(u3); g1 += bhi(u3);
    }
    for (; e < e1; ++e) {
        unsigned uu = hl2[colidx[e] * 32 + f];
        a0 += blo(uu); a1 += bhi(uu);
    }
    float acc0 = (a0 + b0) + (c0 + g0);
    float acc1 = (a1 + b1) + (c1 + g1);
    float dv = dinv[d];
    float o0 = fmaf(acc0, dv, b[2 * f]);
    float o1 = fmaf(acc1, dv, b[2 * f + 1]);
    ((float2*)out)[d * 32 + f] = make_float2(o0, o1);
}

// BN partial stats: per-feature sum / sumsq per block (no global atomics)
__global__ __launch_bounds__(256) void k_stats(const float* __restrict__ h,
                                               float* __restrict__ part, int N) {
    int j = threadIdx.x & 63, grp = threadIdx.x >> 6;
    float s = 0.0f, q = 0.0f;
    for (int node = blockIdx.x * 4 + grp; node < N; node += gridDim.x * 4) {
        float v = h[node * 64 + j];
        s += v;
        q = fmaf(v, v, q);
    }
    __shared__ float ls[8][64];
    ls[grp][j] = s;
    ls[4 + grp][j] = q;
    __syncthreads();
    if (threadIdx.x < 64) {
        part[blockIdx.x * 128 + j] = ls[0][j] + ls[1][j] + ls[2][j] + ls[3][j];
        part[blockIdx.x * 128 + 64 + j] = ls[4][j] + ls[5][j] + ls[6][j] + ls[7][j];
    }
}

// reduce partials -> stats (deterministic, no atomics)
__global__ __launch_bounds__(128) void k_red(const float* __restrict__ part,
                                             float* __restrict__ stats, int nb) {
    int j = threadIdx.x;
    float s = 0.0f;
    for (int b = 0; b < nb; b++) s += part[b * 128 + j];
    stats[j] = s;
}

// BN normalize (+ optional relu), in place
__global__ __launch_bounds__(256) void k_norm(float* __restrict__ h,
                                              const float* __restrict__ stats,
                                              const float* __restrict__ gamma,
                                              const float* __restrict__ beta,
                                              int total, float invN, int relu) {
    int t = blockIdx.x * 256 + threadIdx.x;
    if (t >= total) return;
    int j = t & 63;
    float mu = stats[j] * invN;
    float var = fmaf(-mu, mu, stats[64 + j] * invN);
    float sc = rsqrtf(var + EPSV) * gamma[j];
    float v = fmaf(h[t] - mu, sc, beta[j]);
    if (relu) v = fmaxf(v, 0.0f);
    h[t] = v;
}

// classifier: out = relu(h@W1+b1) @ W2 + b2
__global__ __launch_bounds__(256) void k_cls(const float* __restrict__ h,
                                             const float* __restrict__ W1,
                                             const float* __restrict__ b1,
                                             const float* __restrict__ W2,
                                             const float* __restrict__ b2,
                                             float* __restrict__ out, int N) {
    int lane = threadIdx.x & 63;
    int half = lane >> 5, jj = lane & 31;
    float w[64];
#pragma unroll
    for (int k = 0; k < 64; k++) w[k] = W1[k * 32 + jj];
    float bj = b1[jj];
    float w20 = W2[jj * 2 + 0], w21 = W2[jj * 2 + 1];
    float b20 = b2[0], b21 = b2[1];
    int wave = (blockIdx.x * 256 + threadIdx.x) >> 6;
    int nw = (gridDim.x * 256) >> 6;
    for (int base = wave * 2; base < N; base += nw * 2) {
        int node = base + half;
        int vnode = node < N ? node : 0;
        const float4* row = (const float4*)(h + vnode * 64);
        float acc = bj;
#pragma unroll
        for (int kk = 0; kk < 16; kk++) {
            float4 r = row[kk];
            acc = fmaf(r.x, w[4 * kk + 0], acc);
            acc = fmaf(r.y, w[4 * kk + 1], acc);
            acc = fmaf(r.z, w[4 * kk + 2], acc);
            acc = fmaf(r.w, w[4 * kk + 3], acc);
        }
        float h2 = fmaxf(acc, 0.0f);
        float t0 = h2 * w20, t1 = h2 * w21;
#pragma unroll
        for (int m = 1; m <= 16; m <<= 1) {
            t0 += __shfl_xor(t0, m, 64);
            t1 += __shfl_xor(t1, m, 64);
        }
        if (jj == 0 && node < N) {
            ((float2*)out)[node] = make_float2(t0 + b20, t1 + b21);
        }
    }
}

// ---- fallback (atomic scatter) kernels ----
__global__ __launch_bounds__(256) void k_gemm_fb(const float* __restrict__ W,
                                                 const float* __restrict__ b,
                                                 const float* __restrict__ dinv,
                                                 float* __restrict__ h,
                                                 float* __restrict__ hlin, int N) {
    int j = threadIdx.x & 63;
    float w[64];
#pragma unroll
    for (int k = 0; k < 64; k++) w[k] = W[k * 64 + j];
    float bj = b[j];
    int wave = (blockIdx.x * 256 + threadIdx.x) >> 6;
    int nw = (gridDim.x * 256) >> 6;
    for (int node = wave; node < N; node += nw) {
        const float4* row = (const float4*)(h + node * 64);
        float acc = 0.0f;
#pragma unroll
        for (int kk = 0; kk < 16; kk++) {
            float4 r = row[kk];
            acc = fmaf(r.x, w[4 * kk + 0], acc);
            acc = fmaf(r.y, w[4 * kk + 1], acc);
            acc = fmaf(r.z, w[4 * kk + 2], acc);
            acc = fmaf(r.w, w[4 * kk + 3], acc);
        }
        float dv = dinv[node];
        hlin[node * 64 + j] = acc;
        h[node * 64 + j] = fmaf(acc, dv * dv, bj);
    }
}

__global__ __launch_bounds__(256) void k_edge(const int* __restrict__ src,
                                              const int* __restrict__ dst,
                                              const float* __restrict__ dinv,
                                              const float* __restrict__ hlin,
                                              float* __restrict__ agg, int E) {
    int wave = (blockIdx.x * 256 + threadIdx.x) >> 6;
    int lane = threadIdx.x & 63;
    if (wave >= E) return;
    int s = src[wave], d = dst[wave];
    float nrm = dinv[s] * dinv[d];
    float v = hlin[s * 64 + lane];
    unsafeAtomicAdd(&agg[d * 64 + lane], v * nrm);
}

__global__ __launch_bounds__(256) void k_deg_fb(const int* __restrict__ dst,
                                                int* __restrict__ deg, int E) {
    int i = blockIdx.x * 256 + threadIdx.x;
    if (i < E) atomicAdd(&deg[dst[i]], 1);
}

__global__ __launch_bounds__(256) void k_dinv_fb(const int* __restrict__ deg,
                                                 float* __restrict__ dinv, int N) {
    int i = blockIdx.x * 256 + threadIdx.x;
    if (i < N) dinv[i] = rsqrtf((float)deg[i] + 1.0f);
}

extern "C" void kernel_launch(void* const* d_in, const int* in_sizes, int n_in,
                              void* d_out, int out_size, void* d_ws, size_t ws_size,
                              hipStream_t stream) {
    const float* x     = (const float*)d_in[0];
    const int*   ei    = (const int*)d_in[1];
    const float* Win   = (const float*)d_in[2];
    const float* bin   = (const float*)d_in[3];
    const float* Wg    = (const float*)d_in[4];
    const float* bg    = (const float*)d_in[5];
    const float* gamma = (const float*)d_in[6];
    const float* beta  = (const float*)d_in[7];
    const float* W1    = (const float*)d_in[8];
    const float* b1    = (const float*)d_in[9];
    const float* W2    = (const float*)d_in[10];
    const float* b2    = (const float*)d_in[11];
    float* out = (float*)d_out;

    int N = in_sizes[0] / 12;
    int E = in_sizes[1] / 2;
    const int* src = ei;
    const int* dst = ei + E;
    float invN = 1.0f / (float)N;
    const int SB = 104;  // stats partial blocks

    char* ws = (char*)d_ws;
    size_t szh   = (size_t)N * 64 * sizeof(float);                       // 25.6 MB
    size_t szhl  = (((size_t)N * 64 * 2) + 255) / 256 * 256;             // 12.8 MB bf16
    size_t szE   = ((size_t)E * sizeof(int) + 255) / 256 * 256;          // 12.8 MB
    size_t szN   = ((size_t)N * sizeof(int) + 255) / 256 * 256;          // 0.4 MB
    size_t szN8  = NSHARD * szN;                                         // 3.2 MB
    size_t need = szh + szhl + szE + 2 * szN8 + 4 * szN + 4096 + SB * 128 * 4 + 2048;

    if (ws_size >= need) {
        size_t off = 0;
        float* bufA  = (float*)(ws + off); off += szh;
        __hip_bfloat16* hl = (__hip_bfloat16*)(ws + off); off += szhl;
        int* colidx  = (int*)(ws + off); off += szE;
        int* cnt8    = (int*)(ws + off); off += szN8;
        int* cur8    = (int*)(ws + off); off += szN8;
        int* deg     = (int*)(ws + off); off += szN;
        int* rowptr  = (int*)(ws + off); off += szN;
        int* rowend  = (int*)(ws + off); off += szN;
        float* dinv  = (float*)(ws + off); off += szN;
        int* bsum    = (int*)(ws + off); off += 4096;
        float* part  = (float*)(ws + off); off += SB * 128 * 4;
        float* stats = (float*)(ws + off);

        hipMemsetAsync(cnt8, 0, szN8, stream);

        k_count<<<(E + 255) / 256, 256, 0, stream>>>(dst, cnt8, E, N);
        k_deg8<<<(N + 255) / 256, 256, 0, stream>>>(cnt8, deg, N);
        int B = (N + 1023) / 1024;
        k_scan1<<<B, 256, 0, stream>>>(deg, rowptr, bsum, N);
        k_scan2<<<1, 256, 0, stream>>>(bsum, B);
        k_scan3<<<(N + 255) / 256, 256, 0, stream>>>(rowptr, bsum, N);
        k_curs<<<(N + 255) / 256, 256, 0, stream>>>(cnt8, rowptr, cur8, rowend, dinv, N);
        k_fill<<<(E + 255) / 256, 256, 0, stream>>>(src, dst, cur8, colidx, E, N);

        k_input<<<(N * 64 + 255) / 256, 256, 0, stream>>>(x, Win, bin, bufA, N);

        for (int i = 0; i < 3; i++) {
            k_gemm<<<1024, 256, 0, stream>>>(Wg + i * 64 * 64, dinv, bufA, hl, N);
            k_agg<<<(N + 7) / 8, 256, 0, stream>>>(rowptr, rowend, colidx, dinv,
                                                   (const unsigned*)hl, bg + i * 64,
                                                   bufA, N);
            k_stats<<<SB, 256, 0, stream>>>(bufA, part, N);
            k_red<<<1, 128, 0, stream>>>(part, stats, SB);
            k_norm<<<(N * 64 + 255) / 256, 256, 0, stream>>>(
                bufA, stats, gamma + i * 64, beta + i * 64, N * 64, invN,
                (i < 2) ? 1 : 0);
        }
        k_cls<<<2048, 256, 0, stream>>>(bufA, W1, b1, W2, b2, out, N);
    } else {
        // fallback: atomic scatter path
        float* bufA  = (float*)ws;
        float* bufB  = (float*)(ws + szh);
        int* deg     = (int*)(ws + 2 * szh);
        float* dinv  = (float*)(ws + 2 * szh + szN);
        float* part  = (float*)(ws + 2 * szh + 2 * szN);
        float* stats = (float*)(ws + 2 * szh + 2 * szN + SB * 128 * 4);

        hipMemsetAsync(deg, 0, (size_t)N * sizeof(int), stream);

        k_deg_fb<<<(E + 255) / 256, 256, 0, stream>>>(dst, deg, E);
        k_dinv_fb<<<(N + 255) / 256, 256, 0, stream>>>(deg, dinv, N);
        k_input<<<(N * 64 + 255) / 256, 256, 0, stream>>>(x, Win, bin, bufA, N);

        for (int i = 0; i < 3; i++) {
            k_gemm_fb<<<1024, 256, 0, stream>>>(Wg + i * 64 * 64, bg + i * 64, dinv,
                                                bufA, bufB, N);
            k_edge<<<(E + 3) / 4, 256, 0, stream>>>(src, dst, dinv, bufB, bufA, E);
            k_stats<<<SB, 256, 0, stream>>>(bufA, part, N);
            k_red<<<1, 128, 0, stream>>>(part, stats, SB);
            k_norm<<<(N * 64 + 255) / 256, 256, 0, stream>>>(
                bufA, stats, gamma + i * 64, beta + i * 64, N * 64, invN,
                (i < 2) ? 1 : 0);
        }
        k_cls<<<2048, 256, 0, stream>>>(bufA, W1, b1, W2, b2, out, N);
    }
}

// Round 6
// 900.087 us; speedup vs baseline: 1.3350x; 1.3350x over previous
//
#include <hip/hip_runtime.h>
#include <hip/hip_bf16.h>

#define EPSV 1e-5f

// bf16x2 unpack (bf16 = top 16 bits of fp32)
__device__ inline float blo(unsigned u) { return __uint_as_float(u << 16); }
__device__ inline float bhi(unsigned u) { return __uint_as_float(u & 0xFFFF0000u); }

// ================= CSR build: two-phase multisplit =================
// bucket = dst >> 8 (256 nodes per bucket), NB <= 1024 (N <= 256K)

__global__ __launch_bounds__(256) void k_hist(const int* __restrict__ dst,
                                              int* __restrict__ bcount, int E) {
    __shared__ int hist[1024];
    int t = threadIdx.x;
#pragma unroll
    for (int i = 0; i < 4; i++) hist[t + 256 * i] = 0;
    __syncthreads();
    int e0 = blockIdx.x * 4096;
#pragma unroll
    for (int r = 0; r < 16; r++) {
        int e = e0 + r * 256 + t;
        if (e < E) atomicAdd(&hist[dst[e] >> 8], 1);
    }
    __syncthreads();
#pragma unroll
    for (int i = 0; i < 4; i++) {
        int bk = t + 256 * i;
        int h = hist[bk];
        if (h) atomicAdd(&bcount[bk], h);
    }
}

__global__ __launch_bounds__(256) void k_bscan(const int* __restrict__ bcount,
                                               int* __restrict__ bstart,
                                               int* __restrict__ gcur, int NB) {
    int t = threadIdx.x;
    int base = t * 4;
    int c[4], s = 0;
#pragma unroll
    for (int i = 0; i < 4; i++) {
        c[i] = (base + i < NB) ? bcount[base + i] : 0;
        s += c[i];
    }
    __shared__ int ls[256];
    ls[t] = s;
    __syncthreads();
    for (int off = 1; off < 256; off <<= 1) {
        int x = (t >= off) ? ls[t - off] : 0;
        __syncthreads();
        ls[t] += x;
        __syncthreads();
    }
    int run = (t == 0) ? 0 : ls[t - 1];
#pragma unroll
    for (int i = 0; i < 4; i++) {
        bstart[base + i] = run;
        gcur[base + i] = run;
        run += c[i];
    }
    if (t == 255) bstart[1024] = ls[255];
}

__global__ __launch_bounds__(256) void k_split(const int* __restrict__ src,
                                               const int* __restrict__ dst,
                                               int* __restrict__ gcur,
                                               int2* __restrict__ pairs, int E) {
    __shared__ int hist[1024];   // reused as rank counters in pass 2
    __shared__ int gb[1024];
    int t = threadIdx.x;
    int e0 = blockIdx.x * 4096;
    int sreg[16], dreg[16];
#pragma unroll
    for (int i = 0; i < 4; i++) hist[t + 256 * i] = 0;
    __syncthreads();
#pragma unroll
    for (int r = 0; r < 16; r++) {
        int e = e0 + r * 256 + t;
        if (e < E) {
            sreg[r] = src[e];
            dreg[r] = dst[e];
            atomicAdd(&hist[dreg[r] >> 8], 1);
        } else {
            dreg[r] = -1;
        }
    }
    __syncthreads();
#pragma unroll
    for (int i = 0; i < 4; i++) {
        int bk = t + 256 * i;
        int h = hist[bk];
        gb[bk] = h ? atomicAdd(&gcur[bk], h) : 0;
    }
    __syncthreads();
#pragma unroll
    for (int i = 0; i < 4; i++) hist[t + 256 * i] = 0;
    __syncthreads();
#pragma unroll
    for (int r = 0; r < 16; r++) {
        if (dreg[r] >= 0) {
            int bk = dreg[r] >> 8;
            int rk = atomicAdd(&hist[bk], 1);
            pairs[gb[bk] + rk] = make_int2(sreg[r], dreg[r]);
        }
    }
}

__global__ __launch_bounds__(256) void k_build(const int2* __restrict__ pairs,
                                               const int* __restrict__ bstart,
                                               int* __restrict__ rowptr,
                                               int* __restrict__ rowend,
                                               float* __restrict__ dinv,
                                               int* __restrict__ colidx, int N) {
    int bid = blockIdx.x, t = threadIdx.x;
    int n0 = bid << 8;
    int e0 = bstart[bid], e1 = bstart[bid + 1];
    __shared__ int cnt[256];
    __shared__ int ls[256];
    __shared__ int cur[256];
    cnt[t] = 0;
    __syncthreads();
    for (int e = e0 + t; e < e1; e += 256)
        atomicAdd(&cnt[pairs[e].y - n0], 1);
    __syncthreads();
    ls[t] = cnt[t];
    __syncthreads();
    for (int off = 1; off < 256; off <<= 1) {
        int x = (t >= off) ? ls[t - off] : 0;
        __syncthreads();
        ls[t] += x;
        __syncthreads();
    }
    int start = e0 + ((t == 0) ? 0 : ls[t - 1]);
    cur[t] = start;
    int node = n0 + t;
    if (node < N) {
        rowptr[node] = start;
        rowend[node] = start + cnt[t];
        dinv[node] = rsqrtf((float)cnt[t] + 1.0f);
    }
    __syncthreads();
    for (int e = e0 + t; e < e1; e += 256) {
        int2 p = pairs[e];
        int r = atomicAdd(&cur[p.y - n0], 1);
        colidx[r] = p.x;
    }
}

// ================= network (round-3-verbatim, fp32 h / bf16 hl) =========

// h0 = relu(x @ W_in + b_in); wave per node, lane = out feature
__global__ __launch_bounds__(256) void k_input(const float* __restrict__ x,
                                               const float* __restrict__ Win,
                                               const float* __restrict__ bin,
                                               float* __restrict__ h, int N) {
    int t = blockIdx.x * 256 + threadIdx.x;
    int node = t >> 6, j = t & 63;
    if (node >= N) return;
    const float* xr = x + node * 12;
    float acc = bin[j];
#pragma unroll
    for (int k = 0; k < 12; k++) acc = fmaf(xr[k], Win[k * 64 + j], acc);
    h[t] = fmaxf(acc, 0.0f);
}

// hl (bf16) <- (h @ W) * dinv[node]
__global__ __launch_bounds__(256) void k_gemm(const float* __restrict__ W,
                                              const float* __restrict__ dinv,
                                              const float* __restrict__ h,
                                              __hip_bfloat16* __restrict__ hl, int N) {
    int j = threadIdx.x & 63;
    float w[64];
#pragma unroll
    for (int k = 0; k < 64; k++) w[k] = W[k * 64 + j];
    int wave = (blockIdx.x * 256 + threadIdx.x) >> 6;
    int nw = (gridDim.x * 256) >> 6;
    for (int node = wave; node < N; node += nw) {
        const float4* row = (const float4*)(h + node * 64);
        float acc = 0.0f;
#pragma unroll
        for (int kk = 0; kk < 16; kk++) {
            float4 r = row[kk];
            acc = fmaf(r.x, w[4 * kk + 0], acc);
            acc = fmaf(r.y, w[4 * kk + 1], acc);
            acc = fmaf(r.z, w[4 * kk + 2], acc);
            acc = fmaf(r.w, w[4 * kk + 3], acc);
        }
        hl[node * 64 + j] = __float2bfloat16(acc * dinv[node]);
    }
}

// gather: out[d] = dinv[d]*(hl[d] + sum_{s in in(d)} hl[s]) + b
// half-wave (32 lanes) per dst row; lane holds bf16x2 feature pair.
__global__ __launch_bounds__(256) void k_agg(const int* __restrict__ rowptr,
                                             const int* __restrict__ rowend,
                                             const int* __restrict__ colidx,
                                             const float* __restrict__ dinv,
                                             const unsigned* __restrict__ hl2,
                                             const float* __restrict__ b,
                                             float* __restrict__ out, int N) {
    int t = threadIdx.x;
    int hw = t >> 5, f = t & 31;
    int d = blockIdx.x * 8 + hw;
    if (d >= N) return;
    int e0 = rowptr[d], e1 = rowend[d];
    unsigned us = hl2[d * 32 + f];
    float a0 = blo(us), a1 = bhi(us);
    float b0 = 0.f, b1 = 0.f, c0 = 0.f, c1 = 0.f, g0 = 0.f, g1 = 0.f;
    int e = e0;
    for (; e + 4 <= e1; e += 4) {
        int s0 = colidx[e], s1 = colidx[e + 1], s2 = colidx[e + 2], s3 = colidx[e + 3];
        unsigned u0 = hl2[s0 * 32 + f], u1 = hl2[s1 * 32 + f];
        unsigned u2 = hl2[s2 * 32 + f], u3 = hl2[s3 * 32 + f];
        a0 += blo(u0); a1 += bhi(u0);
        b0 += blo(u1); b1 += bhi(u1);
        c0 += blo(u2); c1 += bhi(u2);
        g0 += blo(u3); g1 += bhi(u3);
    }
    for (; e < e1; ++e) {
        unsigned uu = hl2[colidx[e] * 32 + f];
        a0 += blo(uu); a1 += bhi(uu);
    }
    float acc0 = (a0 + b0) + (c0 + g0);
    float acc1 = (a1 + b1) + (c1 + g1);
    float dv = dinv[d];
    float o0 = fmaf(acc0, dv, b[2 * f]);
    float o1 = fmaf(acc1, dv, b[2 * f + 1]);
    ((float2*)out)[d * 32 + f] = make_float2(o0, o1);
}

// BN partial stats: per-feature sum / sumsq per block (no global atomics)
__global__ __launch_bounds__(256) void k_stats(const float* __restrict__ h,
                                               float* __restrict__ part, int N) {
    int j = threadIdx.x & 63, grp = threadIdx.x >> 6;
    float s = 0.0f, q = 0.0f;
    for (int node = blockIdx.x * 4 + grp; node < N; node += gridDim.x * 4) {
        float v = h[node * 64 + j];
        s += v;
        q = fmaf(v, v, q);
    }
    __shared__ float ls[8][64];
    ls[grp][j] = s;
    ls[4 + grp][j] = q;
    __syncthreads();
    if (threadIdx.x < 64) {
        part[blockIdx.x * 128 + j] = ls[0][j] + ls[1][j] + ls[2][j] + ls[3][j];
        part[blockIdx.x * 128 + 64 + j] = ls[4][j] + ls[5][j] + ls[6][j] + ls[7][j];
    }
}

// reduce partials -> stats (deterministic, no atomics)
__global__ __launch_bounds__(128) void k_red(const float* __restrict__ part,
                                             float* __restrict__ stats, int nb) {
    int j = threadIdx.x;
    float s = 0.0f;
    for (int b = 0; b < nb; b++) s += part[b * 128 + j];
    stats[j] = s;
}

// BN normalize (+ optional relu), in place
__global__ __launch_bounds__(256) void k_norm(float* __restrict__ h,
                                              const float* __restrict__ stats,
                                              const float* __restrict__ gamma,
                                              const float* __restrict__ beta,
                                              int total, float invN, int relu) {
    int t = blockIdx.x * 256 + threadIdx.x;
    if (t >= total) return;
    int j = t & 63;
    float mu = stats[j] * invN;
    float var = fmaf(-mu, mu, stats[64 + j] * invN);
    float sc = rsqrtf(var + EPSV) * gamma[j];
    float v = fmaf(h[t] - mu, sc, beta[j]);
    if (relu) v = fmaxf(v, 0.0f);
    h[t] = v;
}

// classifier: out = relu(h@W1+b1) @ W2 + b2
__global__ __launch_bounds__(256) void k_cls(const float* __restrict__ h,
                                             const float* __restrict__ W1,
                                             const float* __restrict__ b1,
                                             const float* __restrict__ W2,
                                             const float* __restrict__ b2,
                                             float* __restrict__ out, int N) {
    int lane = threadIdx.x & 63;
    int half = lane >> 5, jj = lane & 31;
    float w[64];
#pragma unroll
    for (int k = 0; k < 64; k++) w[k] = W1[k * 32 + jj];
    float bj = b1[jj];
    float w20 = W2[jj * 2 + 0], w21 = W2[jj * 2 + 1];
    float b20 = b2[0], b21 = b2[1];
    int wave = (blockIdx.x * 256 + threadIdx.x) >> 6;
    int nw = (gridDim.x * 256) >> 6;
    for (int base = wave * 2; base < N; base += nw * 2) {
        int node = base + half;
        int vnode = node < N ? node : 0;
        const float4* row = (const float4*)(h + vnode * 64);
        float acc = bj;
#pragma unroll
        for (int kk = 0; kk < 16; kk++) {
            float4 r = row[kk];
            acc = fmaf(r.x, w[4 * kk + 0], acc);
            acc = fmaf(r.y, w[4 * kk + 1], acc);
            acc = fmaf(r.z, w[4 * kk + 2], acc);
            acc = fmaf(r.w, w[4 * kk + 3], acc);
        }
        float h2 = fmaxf(acc, 0.0f);
        float t0 = h2 * w20, t1 = h2 * w21;
#pragma unroll
        for (int m = 1; m <= 16; m <<= 1) {
            t0 += __shfl_xor(t0, m, 64);
            t1 += __shfl_xor(t1, m, 64);
        }
        if (jj == 0 && node < N) {
            ((float2*)out)[node] = make_float2(t0 + b20, t1 + b21);
        }
    }
}

extern "C" void kernel_launch(void* const* d_in, const int* in_sizes, int n_in,
                              void* d_out, int out_size, void* d_ws, size_t ws_size,
                              hipStream_t stream) {
    const float* x     = (const float*)d_in[0];
    const int*   ei    = (const int*)d_in[1];
    const float* Win   = (const float*)d_in[2];
    const float* bin   = (const float*)d_in[3];
    const float* Wg    = (const float*)d_in[4];
    const float* bg    = (const float*)d_in[5];
    const float* gamma = (const float*)d_in[6];
    const float* beta  = (const float*)d_in[7];
    const float* W1    = (const float*)d_in[8];
    const float* b1    = (const float*)d_in[9];
    const float* W2    = (const float*)d_in[10];
    const float* b2    = (const float*)d_in[11];
    float* out = (float*)d_out;

    int N = in_sizes[0] / 12;
    int E = in_sizes[1] / 2;
    const int* src = ei;
    const int* dst = ei + E;
    float invN = 1.0f / (float)N;
    int NB = (N + 255) >> 8;   // buckets
    const int SB = 104;        // stats partial blocks

    char* ws = (char*)d_ws;
    size_t szh  = (size_t)N * 64 * sizeof(float);            // fp32 h
    size_t szhl = ((size_t)N * 64 * 2 + 255) / 256 * 256;    // bf16 hl
    size_t szE4 = ((size_t)E * 4 + 255) / 256 * 256;
    size_t szN4 = ((size_t)N * 4 + 255) / 256 * 256;

    size_t off = 0;
    float* bufA        = (float*)(ws + off); off += szh;
    __hip_bfloat16* hl = (__hip_bfloat16*)(ws + off); off += szhl;
    int* colidx        = (int*)(ws + off); off += szE4;
    int* rowptr        = (int*)(ws + off); off += szN4;
    int* rowend        = (int*)(ws + off); off += szN4;
    float* dinv        = (float*)(ws + off); off += szN4;
    int* bcount        = (int*)(ws + off); off += 4096;
    int* bstart        = (int*)(ws + off); off += 8192;   // 1025 ints
    int* gcur          = (int*)(ws + off); off += 4096;
    float* part        = (float*)(ws + off); off += (size_t)SB * 128 * 4;
    float* stats       = (float*)(ws + off); off += 512;

    // pairs buffer aliases [bufA | hl] (only used before k_input)
    int2* pairs = (int2*)ws;
    size_t need = off;
    if (szh + szhl < (size_t)E * 8) {
        pairs = (int2*)(ws + off);
        need += (size_t)E * 8;
    }
    if (ws_size < need || NB > 1024) return;  // loud failure, no corruption

    hipMemsetAsync(bcount, 0, 4096, stream);

    int EB = (E + 4095) / 4096;
    k_hist<<<EB, 256, 0, stream>>>(dst, bcount, E);
    k_bscan<<<1, 256, 0, stream>>>(bcount, bstart, gcur, NB);
    k_split<<<EB, 256, 0, stream>>>(src, dst, gcur, pairs, E);
    k_build<<<NB, 256, 0, stream>>>(pairs, bstart, rowptr, rowend, dinv, colidx, N);

    k_input<<<(N * 64 + 255) / 256, 256, 0, stream>>>(x, Win, bin, bufA, N);

    for (int i = 0; i < 3; i++) {
        k_gemm<<<1024, 256, 0, stream>>>(Wg + i * 64 * 64, dinv, bufA, hl, N);
        k_agg<<<(N + 7) / 8, 256, 0, stream>>>(rowptr, rowend, colidx, dinv,
                                               (const unsigned*)hl, bg + i * 64,
                                               bufA, N);
        k_stats<<<SB, 256, 0, stream>>>(bufA, part, N);
        k_red<<<1, 128, 0, stream>>>(part, stats, SB);
        k_norm<<<(N * 64 + 255) / 256, 256, 0, stream>>>(
            bufA, stats, gamma + i * 64, beta + i * 64, N * 64, invN,
            (i < 2) ? 1 : 0);
    }
    k_cls<<<2048, 256, 0, stream>>>(bufA, W1, b1, W2, b2, out, N);
}